// Round 12
// baseline (205.050 us; speedup 1.0000x reference)
//
#include <hip/hip_runtime.h>
#include <hip/hip_bf16.h>

// Problem constants (reference: B=2, S=2048, D=1024, H=16, HD=64)
#define BB 2
#define SS 2048
#define DD 1024
#define HH 16
#define HD 64
#define MM (BB * SS)   // 4096 rows in all GEMMs
#define NQKV 3072      // fused QKV output columns

typedef __attribute__((ext_vector_type(8))) short short8;   // 8 x bf16 frag
typedef __attribute__((ext_vector_type(4))) short s16x4;
typedef __attribute__((ext_vector_type(4))) float floatx4;  // MFMA C/D frag
typedef __attribute__((ext_vector_type(4))) float f32x4;
using bf16 = __hip_bfloat16;

__device__ __forceinline__ float b2f(bf16 x) { return __bfloat162float(x); }
__device__ __forceinline__ short f2bs(float x) {
    bf16 h = __float2bfloat16(x);
    return *reinterpret_cast<short*>(&h);
}
__device__ __forceinline__ float bs2f(short s) {
    bf16 h; *reinterpret_cast<short*>(&h) = s; return __bfloat162float(h);
}

// LDS tiles addressed in 16B chunks (8 shorts), XOR swizzle (chunk ^ (row&7)).
__device__ __forceinline__ int lds_off(int row, int chunk) {
    return row * 64 + ((chunk ^ (row & 7)) * 8);
}

// Direct global->LDS async copy, 16B per lane. LDS dest is wave-uniform base
// + lane*16 (linear); the XOR swizzle is applied on the GLOBAL source address.
#define GL16(gp, lp)                                                        \
    __builtin_amdgcn_global_load_lds(                                       \
        (const __attribute__((address_space(1))) void*)(gp),                \
        (__attribute__((address_space(3))) void*)(lp), 16, 0, 0)

// ---------------------------------------------------------------------------
// Merged converter (r7, unchanged): Wcat | Xb | Wob in ONE launch.
// ---------------------------------------------------------------------------
#define N_WCAT (NQKV * DD / 4)
#define N_X    (MM * DD / 4)
#define N_WOB  (DD * DD / 4)

__global__ __launch_bounds__(256) void convert_all(
    const float* __restrict__ Wq, const float* __restrict__ Wk,
    const float* __restrict__ Wv, const float* __restrict__ X,
    const float* __restrict__ Wo,
    short* __restrict__ wcat, short* __restrict__ xb, short* wob)
{
    const int total = N_WCAT + N_X + (wob ? N_WOB : 0);
    const int stride = gridDim.x * blockDim.x;
    for (int i = blockIdx.x * blockDim.x + threadIdx.x; i < total; i += stride) {
        f32x4 v; short* dp;
        if (i < N_WCAT) {
            const int e = i * 4;
            const int z = e >> 20;
            const int off = e & 0xFFFFF;
            const float* src = (z == 0) ? Wq : (z == 1) ? Wk : Wv;
            v = *(const f32x4*)(src + off);
            dp = wcat + e;
        } else if (i < N_WCAT + N_X) {
            const int e = (i - N_WCAT) * 4;
            v = *(const f32x4*)(X + e);
            dp = xb + e;
        } else {
            const int e = (i - N_WCAT - N_X) * 4;
            v = *(const f32x4*)(Wo + e);
            dp = wob + e;
        }
        s16x4 o; o[0] = f2bs(v[0]); o[1] = f2bs(v[1]); o[2] = f2bs(v[2]); o[3] = f2bs(v[3]);
        *(s16x4*)dp = o;
    }
}

// Fallback single converter (used only when ws is too small to hoist Wob).
__global__ __launch_bounds__(256) void convert_w(
    const float* __restrict__ W, short* __restrict__ dst)
{
    const int stride = gridDim.x * blockDim.x;
    for (int i = blockIdx.x * blockDim.x + threadIdx.x; i < DD * DD / 4; i += stride) {
        f32x4 v = *(const f32x4*)(W + i * 4);
        s16x4 o; o[0] = f2bs(v[0]); o[1] = f2bs(v[1]); o[2] = f2bs(v[2]); o[3] = f2bs(v[3]);
        *(s16x4*)(dst + i * 4) = o;
    }
}

// ---------------------------------------------------------------------------
// Fused QKV GEMM (r19, unchanged): 128x64 tile, 6 blocks/CU. qkv is closed:
// 7 structures all ~53-55 us; MfmaUtil 18% x 53 us ~= the 10.3 us compute
// floor — MFMA pipe already at required average rate.
// ---------------------------------------------------------------------------
__global__ __launch_bounds__(256, 6) void qkv_gemm2(
    const short* __restrict__ Xb, const short* __restrict__ Wcat,
    const float* __restrict__ bq, const float* __restrict__ bk, const float* __restrict__ bv,
    bf16* __restrict__ outQ, bf16* __restrict__ outK, bf16* __restrict__ outV)
{
    __shared__ short As[128 * 64];   // 16 KB
    __shared__ short Bs[64 * 64];    // 8 KB

    const int tid  = threadIdx.x;
    const int lane = tid & 63;
    const int wave = tid >> 6;
    const int wm   = wave & 1;
    const int wn   = wave >> 1;
    const int g    = lane >> 4;
    const int fr   = lane & 15;

    const int m0 = blockIdx.x * 128;
    const int n0 = blockIdx.y * 64;

    const int l8  = lane >> 3;
    const int sch = (lane & 7) ^ l8;
    const short* agl = Xb   + (size_t)(m0 + l8) * DD + sch * 8;
    const short* bgl = Wcat + (size_t)(n0 + l8) * DD + sch * 8;

    floatx4 acc[4][2];
#pragma unroll
    for (int i = 0; i < 4; ++i)
#pragma unroll
        for (int j = 0; j < 2; ++j) acc[i][j] = (floatx4){0.f, 0.f, 0.f, 0.f};

    for (int kb = 0; kb < DD; kb += 64) {
        __syncthreads();
#pragma unroll
        for (int j = 0; j < 4; ++j) {
            const int r = wave * 32 + j * 8;
            GL16(agl + (size_t)r * DD + kb, &As[r * 64]);
        }
#pragma unroll
        for (int j = 0; j < 2; ++j) {
            const int r = wave * 16 + j * 8;
            GL16(bgl + (size_t)r * DD + kb, &Bs[r * 64]);
        }
        __syncthreads();

#pragma unroll
        for (int kk = 0; kk < 2; ++kk) {
            const int kc = kk * 4 + g;
            short8 af[4], bf[2];
#pragma unroll
            for (int t = 0; t < 4; ++t)
                af[t] = *(const short8*)&As[lds_off(wm * 64 + t * 16 + fr, kc)];
#pragma unroll
            for (int u = 0; u < 2; ++u)
                bf[u] = *(const short8*)&Bs[lds_off(wn * 32 + u * 16 + fr, kc)];
#pragma unroll
            for (int mt = 0; mt < 4; ++mt)
#pragma unroll
                for (int nt = 0; nt < 2; ++nt)
                    acc[mt][nt] = __builtin_amdgcn_mfma_f32_16x16x32_bf16(
                        af[mt], bf[nt], acc[mt][nt], 0, 0, 0);
        }
    }

#pragma unroll
    for (int nt = 0; nt < 2; ++nt) {
        const int n  = n0 + wn * 32 + nt * 16 + fr;
        const int z  = n >> 10;
        const int nn = n & 1023;
        const int h_ = nn >> 6;
        const int d_ = nn & 63;
        const float biasv = ((z == 0) ? bq : (z == 1) ? bk : bv)[nn];
        bf16* outp = (z == 0) ? outQ : (z == 1) ? outK : outV;
#pragma unroll
        for (int mt = 0; mt < 4; ++mt) {
#pragma unroll
            for (int reg = 0; reg < 4; ++reg) {
                const int m  = m0 + wm * 64 + mt * 16 + g * 4 + reg;
                const int b_ = m >> 11;
                const int s_ = m & (SS - 1);
                const float v = acc[mt][nt][reg] + biasv;
                size_t off;
                if (z == 2) off = ((size_t)((b_ * HH + h_) * HD + d_)) * SS + s_;  // V^T
                else        off = ((size_t)((b_ * HH + h_) * SS + s_)) * HD + d_;  // Q,K
                outp[off] = __float2bfloat16(v);
            }
        }
    }
}

// ---------------------------------------------------------------------------
// Output projection (r19, unchanged).
// ---------------------------------------------------------------------------
__global__ __launch_bounds__(256, 6) void o_gemm2(
    const short* __restrict__ A, const short* __restrict__ Wob,
    const float* __restrict__ bias, float* __restrict__ out)
{
    __shared__ short As[128 * 64];
    __shared__ short Bs[64 * 64];

    const int tid  = threadIdx.x;
    const int lane = tid & 63;
    const int wave = tid >> 6;
    const int wm   = wave & 1;
    const int wn   = wave >> 1;
    const int g    = lane >> 4;
    const int fr   = lane & 15;

    const int m0 = blockIdx.x * 128;
    const int n0 = blockIdx.y * 64;

    const int l8  = lane >> 3;
    const int sch = (lane & 7) ^ l8;
    const short* agl = A   + (size_t)(m0 + l8) * DD + sch * 8;
    const short* bgl = Wob + (size_t)(n0 + l8) * DD + sch * 8;

    floatx4 acc[4][2];
#pragma unroll
    for (int i = 0; i < 4; ++i)
#pragma unroll
        for (int j = 0; j < 2; ++j) acc[i][j] = (floatx4){0.f, 0.f, 0.f, 0.f};

    for (int kb = 0; kb < DD; kb += 64) {
        __syncthreads();
#pragma unroll
        for (int j = 0; j < 4; ++j) {
            const int r = wave * 32 + j * 8;
            GL16(agl + (size_t)r * DD + kb, &As[r * 64]);
        }
#pragma unroll
        for (int j = 0; j < 2; ++j) {
            const int r = wave * 16 + j * 8;
            GL16(bgl + (size_t)r * DD + kb, &Bs[r * 64]);
        }
        __syncthreads();

#pragma unroll
        for (int kk = 0; kk < 2; ++kk) {
            const int kc = kk * 4 + g;
            short8 af[4], bf[2];
#pragma unroll
            for (int t = 0; t < 4; ++t)
                af[t] = *(const short8*)&As[lds_off(wm * 64 + t * 16 + fr, kc)];
#pragma unroll
            for (int u = 0; u < 2; ++u)
                bf[u] = *(const short8*)&Bs[lds_off(wn * 32 + u * 16 + fr, kc)];
#pragma unroll
            for (int mt = 0; mt < 4; ++mt)
#pragma unroll
                for (int nt = 0; nt < 2; ++nt)
                    acc[mt][nt] = __builtin_amdgcn_mfma_f32_16x16x32_bf16(
                        af[mt], bf[nt], acc[mt][nt], 0, 0, 0);
        }
    }

#pragma unroll
    for (int nt = 0; nt < 2; ++nt) {
        const int n = n0 + wn * 32 + nt * 16 + fr;
        const float biasv = bias[n];
#pragma unroll
        for (int mt = 0; mt < 4; ++mt) {
#pragma unroll
            for (int reg = 0; reg < 4; ++reg) {
                const int m = m0 + wm * 64 + mt * 16 + g * 4 + reg;
                out[(size_t)m * DD + n] = acc[mt][nt][reg] + biasv;
            }
        }
    }
}

// ---------------------------------------------------------------------------
// MFMA flash attention v8: 8-wave blocks, 128-row q-tiles. r11 showed flash
// VALU-bound (VALUBusy 41%, top pipe) at only 25% occupancy (LDS 40 KB ->
// 4 blocks/CU). v8: one block = 8 waves sharing each staged K/V tile.
// Blocks 1024->512; staged-tile reuse 4->8 waves (staging traffic + barrier
// rounds halve); LDS 48 KB -> 3 blocks/CU x 8 waves = 24 waves/CU (75%).
// Per-wave compute/P-path/swizzles byte-identical to v7 (validated).
// Staging: 1 GL16/thread per buffer; wave-uniform dest buf + wave*8*64;
// lane l -> row wave*8+(l>>3), phys chunk l&7 holds src chunk (l&7)^(l>>3)
// (row&7 == l>>3 since wave*8 % 8 == 0) — same involution as v7.
// ---------------------------------------------------------------------------
__global__ __launch_bounds__(512) void flash_mfma8(
    const bf16* __restrict__ Qh,   // [B,H,S,HD]
    const bf16* __restrict__ Kh,   // [B,H,S,HD]
    const bf16* __restrict__ VT,   // [B,H,HD,S]
    const int*  __restrict__ pad,  // [B,S] int32, nonzero = masked key
    bf16* __restrict__ attn)       // [B,S,D]
{
    __shared__ short Ks[2][64 * 64];    // 16 KB (double-buffered)
    __shared__ short Vs[2][64 * 64];    // 16 KB
    __shared__ short Pld[8][16 * 64];   // 16 KB per-wave P tiles

    const int tid  = threadIdx.x;
    const int lane = tid & 63;
    const int wave = tid >> 6;              // 0..7
    const int xcd = blockIdx.x & 7;
    const int idx = blockIdx.x >> 3;        // 0..63
    const int bh  = (xcd << 2) | (idx & 3); // 4 heads per XCD group
    const int qt  = 15 - (idx >> 2);        // 128-row q-tile, longest first
    const int q0  = qt * 128 + wave * 16;
    const int b_  = bh >> 4;
    const int h_  = bh & 15;

    const int g  = lane >> 4;   // 0..3
    const int fr = lane & 15;
    const int k8 = g * 8;

    short* myP = Pld[wave];

    // Q fragments (2 dim-halves), pre-scaled by 1/sqrt(64)=0.125
    const bf16* qbase = Qh + ((size_t)bh * SS + q0 + fr) * HD + k8;
    short8 qf[2];
#pragma unroll
    for (int hh = 0; hh < 2; ++hh) {
        short8 rawq = *(const short8*)((const short*)qbase + hh * 32);
#pragma unroll
        for (int j = 0; j < 8; ++j) qf[hh][j] = f2bs(bs2f(rawq[j]) * 0.125f);
    }

    const int* padrow = pad + b_ * SS;
    const short* kbh = (const short*)(Kh + (size_t)bh * SS * HD);
    const short* vbh = (const short*)(VT + (size_t)bh * HD * SS);

    const int l8  = lane >> 3;          // 0..7 (row within wave's 8-row group)
    const int sch = (lane & 7) ^ l8;    // pre-swizzled source chunk
    const int srow = wave * 8 + l8;     // 0..63
    auto stageKV = [&](int buf, int kb) {
        GL16(kbh + (size_t)(kb + srow) * HD + sch * 8, &Ks[buf][wave * 8 * 64]);
        GL16(vbh + (size_t)srow * SS + kb + sch * 8,   &Vs[buf][wave * 8 * 64]);
    };

    floatx4 o[4] = {{0,0,0,0},{0,0,0,0},{0,0,0,0},{0,0,0,0}};
    float l_acc[4] = {0.f, 0.f, 0.f, 0.f};

    const int kend = qt * 128 + 127;   // uniform across the block

    stageKV(0, 0);
    asm volatile("s_waitcnt vmcnt(0)" ::: "memory");
    __syncthreads();

    for (int kb = 0; kb <= kend; kb += 64) {
        const int cur = (kb >> 6) & 1;
        if (kb + 64 <= kend) stageKV(cur ^ 1, kb + 64);

        const short* Kc = Ks[cur];
        const short* Vc = Vs[cur];

        floatx4 c[4];
        __builtin_amdgcn_s_setprio(1);
#pragma unroll
        for (int t = 0; t < 4; ++t) {
            short8 kf0 = *(const short8*)&Kc[(t * 16 + fr) * 64 + ((g       ^ (fr & 7)) << 3)];
            short8 kf1 = *(const short8*)&Kc[(t * 16 + fr) * 64 + (((g + 4) ^ (fr & 7)) << 3)];
            floatx4 cc = {0, 0, 0, 0};
            cc = __builtin_amdgcn_mfma_f32_16x16x32_bf16(qf[0], kf0, cc, 0, 0, 0);
            cc = __builtin_amdgcn_mfma_f32_16x16x32_bf16(qf[1], kf1, cc, 0, 0, 0);
            c[t] = cc;
        }
        __builtin_amdgcn_s_setprio(0);

        bool pm[4];
#pragma unroll
        for (int t = 0; t < 4; ++t) pm[t] = (padrow[kb + t * 16 + fr] != 0);

#pragma unroll
        for (int reg = 0; reg < 4; ++reg) {
            const int q   = q0 + g * 4 + reg;
            const int row = g * 4 + reg;
#pragma unroll
            for (int t = 0; t < 4; ++t) {
                const int key = kb + t * 16 + fr;
                const float p = (key <= q && !pm[t]) ? __expf(c[t][reg]) : 0.f;
                l_acc[reg] += p;
                const int col = t * 16 + fr;
                myP[row * 64 + (((col >> 3) ^ (row & 7)) << 3) + (col & 7)] = f2bs(p);
            }
        }

        short8 pf0 = *(const short8*)&myP[fr * 64 + ((g       ^ (fr & 7)) << 3)];
        short8 pf1 = *(const short8*)&myP[fr * 64 + (((g + 4) ^ (fr & 7)) << 3)];
        __builtin_amdgcn_s_setprio(1);
#pragma unroll
        for (int n = 0; n < 4; ++n) {
            short8 vf0 = *(const short8*)&Vc[(n * 16 + fr) * 64 + ((g       ^ (fr & 7)) << 3)];
            short8 vf1 = *(const short8*)&Vc[(n * 16 + fr) * 64 + (((g + 4) ^ (fr & 7)) << 3)];
            o[n] = __builtin_amdgcn_mfma_f32_16x16x32_bf16(pf0, vf0, o[n], 0, 0, 0);
            o[n] = __builtin_amdgcn_mfma_f32_16x16x32_bf16(pf1, vf1, o[n], 0, 0, 0);
        }
        __builtin_amdgcn_s_setprio(0);

        asm volatile("s_waitcnt vmcnt(0)" ::: "memory");
        __syncthreads();
    }

    float inv[4];
#pragma unroll
    for (int reg = 0; reg < 4; ++reg) {
        float l = l_acc[reg];
#pragma unroll
        for (int off = 1; off < 16; off <<= 1) l += __shfl_xor(l, off);
        inv[reg] = 1.f / fmaxf(l, 1e-38f);
    }
#pragma unroll
    for (int n = 0; n < 4; ++n) {
#pragma unroll
        for (int reg = 0; reg < 4; ++reg) {
            const int q = q0 + g * 4 + reg;
            attn[((size_t)(b_ * SS + q)) * DD + h_ * HD + n * 16 + fr] =
                __float2bfloat16(o[n][reg] * inv[reg]);
        }
    }
}

// ---------------------------------------------------------------------------
extern "C" void kernel_launch(void* const* d_in, const int* in_sizes, int n_in,
                              void* d_out, int out_size, void* d_ws, size_t ws_size,
                              hipStream_t stream) {
    const float* x   = (const float*)d_in[0];
    const int*   pad = (const int*)  d_in[1];
    const float* Wq  = (const float*)d_in[2];
    const float* bq  = (const float*)d_in[3];
    const float* Wk  = (const float*)d_in[4];
    const float* bk  = (const float*)d_in[5];
    const float* Wv  = (const float*)d_in[6];
    const float* bv  = (const float*)d_in[7];
    const float* Wo  = (const float*)d_in[8];
    const float* bo  = (const float*)d_in[9];
    float* out = (float*)d_out;                  // fp32 output

    const size_t NELEM = (size_t)BB * HH * SS * HD;  // 4,194,304
    bf16* Qh   = (bf16*)d_ws;
    bf16* Kh   = Qh + NELEM;
    bf16* VT   = Kh + NELEM;
    bf16* attn = VT + NELEM;
    // Scratch in d_out (16.78 MB): Wcat 6.29 MB + Xb 8.39 MB, both consumed
    // before o_gemm2 overwrites d_out with the final fp32 result.
    short* Wcat = (short*)d_out;
    short* Xb   = (short*)d_out + (size_t)NQKV * DD;

    // Wob: hoist into ws tail if it fits (single merged convert, 4 launches);
    // else alias Qh and convert after flash (fallback).
    const size_t ws_need = 4 * NELEM * sizeof(bf16) + (size_t)DD * DD * sizeof(short);
    const bool big_ws = ws_size >= ws_need;
    short* Wob = big_ws ? (short*)(attn + NELEM) : (short*)Qh;

    convert_all<<<2048, 256, 0, stream>>>(Wq, Wk, Wv, x, Wo, Wcat, Xb,
                                          big_ws ? Wob : nullptr);

    dim3 gq(MM / 128, NQKV / 64);
    qkv_gemm2<<<gq, 256, 0, stream>>>(Xb, Wcat, bq, bk, bv, Qh, Kh, VT);

    flash_mfma8<<<512, 512, 0, stream>>>(Qh, Kh, VT, pad, attn);

    if (!big_ws) convert_w<<<512, 256, 0, stream>>>(Wo, Wob);

    dim3 go(MM / 128, DD / 64);
    o_gemm2<<<go, 256, 0, stream>>>((const short*)attn, Wob, bo, out);
}

// Round 13
// 189.415 us; speedup vs baseline: 1.0825x; 1.0825x over previous
//
#include <hip/hip_runtime.h>
#include <hip/hip_bf16.h>

// Problem constants (reference: B=2, S=2048, D=1024, H=16, HD=64)
#define BB 2
#define SS 2048
#define DD 1024
#define HH 16
#define HD 64
#define MM (BB * SS)   // 4096 rows in all GEMMs
#define NQKV 3072      // fused QKV output columns

typedef __attribute__((ext_vector_type(8))) short short8;   // 8 x bf16 frag
typedef __attribute__((ext_vector_type(4))) short s16x4;
typedef __attribute__((ext_vector_type(4))) float floatx4;  // MFMA C/D frag
typedef __attribute__((ext_vector_type(4))) float f32x4;
using bf16 = __hip_bfloat16;

__device__ __forceinline__ float b2f(bf16 x) { return __bfloat162float(x); }
__device__ __forceinline__ short f2bs(float x) {
    bf16 h = __float2bfloat16(x);
    return *reinterpret_cast<short*>(&h);
}
__device__ __forceinline__ float bs2f(short s) {
    bf16 h; *reinterpret_cast<short*>(&h) = s; return __bfloat162float(h);
}

// LDS tiles addressed in 16B chunks (8 shorts), XOR swizzle (chunk ^ (row&7)).
__device__ __forceinline__ int lds_off(int row, int chunk) {
    return row * 64 + ((chunk ^ (row & 7)) * 8);
}

// Direct global->LDS async copy, 16B per lane.
#define GL16(gp, lp)                                                        \
    __builtin_amdgcn_global_load_lds(                                       \
        (const __attribute__((address_space(1))) void*)(gp),                \
        (__attribute__((address_space(3))) void*)(lp), 16, 0, 0)

// ---------------------------------------------------------------------------
// Merged converter (r7, unchanged): Wcat | Xb | Wob in ONE launch.
// ---------------------------------------------------------------------------
#define N_WCAT (NQKV * DD / 4)
#define N_X    (MM * DD / 4)
#define N_WOB  (DD * DD / 4)

__global__ __launch_bounds__(256) void convert_all(
    const float* __restrict__ Wq, const float* __restrict__ Wk,
    const float* __restrict__ Wv, const float* __restrict__ X,
    const float* __restrict__ Wo,
    short* __restrict__ wcat, short* __restrict__ xb, short* wob)
{
    const int total = N_WCAT + N_X + (wob ? N_WOB : 0);
    const int stride = gridDim.x * blockDim.x;
    for (int i = blockIdx.x * blockDim.x + threadIdx.x; i < total; i += stride) {
        f32x4 v; short* dp;
        if (i < N_WCAT) {
            const int e = i * 4;
            const int z = e >> 20;
            const int off = e & 0xFFFFF;
            const float* src = (z == 0) ? Wq : (z == 1) ? Wk : Wv;
            v = *(const f32x4*)(src + off);
            dp = wcat + e;
        } else if (i < N_WCAT + N_X) {
            const int e = (i - N_WCAT) * 4;
            v = *(const f32x4*)(X + e);
            dp = xb + e;
        } else {
            const int e = (i - N_WCAT - N_X) * 4;
            v = *(const f32x4*)(Wo + e);
            dp = wob + e;
        }
        s16x4 o; o[0] = f2bs(v[0]); o[1] = f2bs(v[1]); o[2] = f2bs(v[2]); o[3] = f2bs(v[3]);
        *(s16x4*)dp = o;
    }
}

// Fallback single converter (only when ws too small to hoist Wob).
__global__ __launch_bounds__(256) void convert_w(
    const float* __restrict__ W, short* __restrict__ dst)
{
    const int stride = gridDim.x * blockDim.x;
    for (int i = blockIdx.x * blockDim.x + threadIdx.x; i < DD * DD / 4; i += stride) {
        f32x4 v = *(const f32x4*)(W + i * 4);
        s16x4 o; o[0] = f2bs(v[0]); o[1] = f2bs(v[1]); o[2] = f2bs(v[2]); o[3] = f2bs(v[3]);
        *(s16x4*)(dst + i * 4) = o;
    }
}

// ---------------------------------------------------------------------------
// build_idx: per-batch compaction metadata. pad_mask masks ~50% of KEYS for
// every query, so K/V compaction halves flash's tile count (work ~ tiles).
// cidx[b][j] = original s of j-th unmasked key (tail = SS sentinel);
// pfx[b][s]  = inclusive count of unmasked keys <= s.
// One block per batch; 256 threads x 8 elems; Hillis-Steele over partials.
// ---------------------------------------------------------------------------
__global__ __launch_bounds__(256) void build_idx(
    const int* __restrict__ pad, int* __restrict__ cidx, int* __restrict__ pfx)
{
    const int b   = blockIdx.x;
    const int tid = threadIdx.x;
    __shared__ int part[256];
    const int* pr = pad + b * SS;
    int* ci = cidx + b * SS;
    int* pf = pfx + b * SS;

    const int s0 = tid * 8;
    int loc[8]; int sum = 0;
#pragma unroll
    for (int j = 0; j < 8; ++j) { loc[j] = (pr[s0 + j] == 0) ? 1 : 0; sum += loc[j]; }
    part[tid] = sum;
    __syncthreads();
    for (int off = 1; off < 256; off <<= 1) {
        const int v   = part[tid];
        const int add = (tid >= off) ? part[tid - off] : 0;
        __syncthreads();
        part[tid] = v + add;
        __syncthreads();
    }
    int run = (tid > 0) ? part[tid - 1] : 0;
#pragma unroll
    for (int j = 0; j < 8; ++j) {
        run += loc[j];
        pf[s0 + j] = run;
        if (loc[j]) ci[run - 1] = s0 + j;
    }
    const int total = part[255];
    for (int j = total + tid; j < SS; j += 256) ci[j] = SS;  // sentinel tail
}

// ---------------------------------------------------------------------------
// Fused QKV GEMM (r19 structure, 128x64 tile, 6 blocks/CU — closed at its
// floor). Epilogue change: K and V are written COMPACTED (masked key rows
// skipped; unmasked row s -> compact slot pfx[s]-1). Kc row-major per head;
// VTc transposed [HD][S]. Kc/VTc are pre-zeroed (memset) so tails are 0.
// ---------------------------------------------------------------------------
__global__ __launch_bounds__(256, 6) void qkv_gemm2(
    const short* __restrict__ Xb, const short* __restrict__ Wcat,
    const float* __restrict__ bq, const float* __restrict__ bk, const float* __restrict__ bv,
    const int* __restrict__ pad, const int* __restrict__ pfx,
    bf16* __restrict__ outQ, bf16* __restrict__ outKc, bf16* __restrict__ outVTc)
{
    __shared__ short As[128 * 64];   // 16 KB
    __shared__ short Bs[64 * 64];    // 8 KB

    const int tid  = threadIdx.x;
    const int lane = tid & 63;
    const int wave = tid >> 6;
    const int wm   = wave & 1;
    const int wn   = wave >> 1;
    const int g    = lane >> 4;
    const int fr   = lane & 15;

    const int m0 = blockIdx.x * 128;
    const int n0 = blockIdx.y * 64;

    const int l8  = lane >> 3;
    const int sch = (lane & 7) ^ l8;
    const short* agl = Xb   + (size_t)(m0 + l8) * DD + sch * 8;
    const short* bgl = Wcat + (size_t)(n0 + l8) * DD + sch * 8;

    floatx4 acc[4][2];
#pragma unroll
    for (int i = 0; i < 4; ++i)
#pragma unroll
        for (int j = 0; j < 2; ++j) acc[i][j] = (floatx4){0.f, 0.f, 0.f, 0.f};

    for (int kb = 0; kb < DD; kb += 64) {
        __syncthreads();
#pragma unroll
        for (int j = 0; j < 4; ++j) {
            const int r = wave * 32 + j * 8;
            GL16(agl + (size_t)r * DD + kb, &As[r * 64]);
        }
#pragma unroll
        for (int j = 0; j < 2; ++j) {
            const int r = wave * 16 + j * 8;
            GL16(bgl + (size_t)r * DD + kb, &Bs[r * 64]);
        }
        __syncthreads();

#pragma unroll
        for (int kk = 0; kk < 2; ++kk) {
            const int kc = kk * 4 + g;
            short8 af[4], bf[2];
#pragma unroll
            for (int t = 0; t < 4; ++t)
                af[t] = *(const short8*)&As[lds_off(wm * 64 + t * 16 + fr, kc)];
#pragma unroll
            for (int u = 0; u < 2; ++u)
                bf[u] = *(const short8*)&Bs[lds_off(wn * 32 + u * 16 + fr, kc)];
#pragma unroll
            for (int mt = 0; mt < 4; ++mt)
#pragma unroll
                for (int nt = 0; nt < 2; ++nt)
                    acc[mt][nt] = __builtin_amdgcn_mfma_f32_16x16x32_bf16(
                        af[mt], bf[nt], acc[mt][nt], 0, 0, 0);
        }
    }

#pragma unroll
    for (int nt = 0; nt < 2; ++nt) {
        const int n  = n0 + wn * 32 + nt * 16 + fr;
        const int z  = n >> 10;          // uniform per block (n0 64-aligned)
        const int nn = n & 1023;
        const int h_ = nn >> 6;
        const int d_ = nn & 63;
        const float biasv = ((z == 0) ? bq : (z == 1) ? bk : bv)[nn];
#pragma unroll
        for (int mt = 0; mt < 4; ++mt) {
#pragma unroll
            for (int reg = 0; reg < 4; ++reg) {
                const int m  = m0 + wm * 64 + mt * 16 + g * 4 + reg;
                const int b_ = m >> 11;
                const int s_ = m & (SS - 1);
                const float v = acc[mt][nt][reg] + biasv;
                if (z == 0) {
                    outQ[((size_t)((b_ * HH + h_) * SS + s_)) * HD + d_] =
                        __float2bfloat16(v);
                } else if (pad[b_ * SS + s_] == 0) {
                    const int cs = pfx[b_ * SS + s_] - 1;   // compact slot
                    if (z == 1)
                        outKc[((size_t)((b_ * HH + h_) * SS + cs)) * HD + d_] =
                            __float2bfloat16(v);
                    else
                        outVTc[((size_t)((b_ * HH + h_) * HD + d_)) * SS + cs] =
                            __float2bfloat16(v);
                }
            }
        }
    }
}

// ---------------------------------------------------------------------------
// Output projection (r19, unchanged).
// ---------------------------------------------------------------------------
__global__ __launch_bounds__(256, 6) void o_gemm2(
    const short* __restrict__ A, const short* __restrict__ Wob,
    const float* __restrict__ bias, float* __restrict__ out)
{
    __shared__ short As[128 * 64];
    __shared__ short Bs[64 * 64];

    const int tid  = threadIdx.x;
    const int lane = tid & 63;
    const int wave = tid >> 6;
    const int wm   = wave & 1;
    const int wn   = wave >> 1;
    const int g    = lane >> 4;
    const int fr   = lane & 15;

    const int m0 = blockIdx.x * 128;
    const int n0 = blockIdx.y * 64;

    const int l8  = lane >> 3;
    const int sch = (lane & 7) ^ l8;
    const short* agl = A   + (size_t)(m0 + l8) * DD + sch * 8;
    const short* bgl = Wob + (size_t)(n0 + l8) * DD + sch * 8;

    floatx4 acc[4][2];
#pragma unroll
    for (int i = 0; i < 4; ++i)
#pragma unroll
        for (int j = 0; j < 2; ++j) acc[i][j] = (floatx4){0.f, 0.f, 0.f, 0.f};

    for (int kb = 0; kb < DD; kb += 64) {
        __syncthreads();
#pragma unroll
        for (int j = 0; j < 4; ++j) {
            const int r = wave * 32 + j * 8;
            GL16(agl + (size_t)r * DD + kb, &As[r * 64]);
        }
#pragma unroll
        for (int j = 0; j < 2; ++j) {
            const int r = wave * 16 + j * 8;
            GL16(bgl + (size_t)r * DD + kb, &Bs[r * 64]);
        }
        __syncthreads();

#pragma unroll
        for (int kk = 0; kk < 2; ++kk) {
            const int kc = kk * 4 + g;
            short8 af[4], bf[2];
#pragma unroll
            for (int t = 0; t < 4; ++t)
                af[t] = *(const short8*)&As[lds_off(wm * 64 + t * 16 + fr, kc)];
#pragma unroll
            for (int u = 0; u < 2; ++u)
                bf[u] = *(const short8*)&Bs[lds_off(wn * 32 + u * 16 + fr, kc)];
#pragma unroll
            for (int mt = 0; mt < 4; ++mt)
#pragma unroll
                for (int nt = 0; nt < 2; ++nt)
                    acc[mt][nt] = __builtin_amdgcn_mfma_f32_16x16x32_bf16(
                        af[mt], bf[nt], acc[mt][nt], 0, 0, 0);
        }
    }

#pragma unroll
    for (int nt = 0; nt < 2; ++nt) {
        const int n = n0 + wn * 32 + nt * 16 + fr;
        const float biasv = bias[n];
#pragma unroll
        for (int mt = 0; mt < 4; ++mt) {
#pragma unroll
            for (int reg = 0; reg < 4; ++reg) {
                const int m = m0 + wm * 64 + mt * 16 + g * 4 + reg;
                out[(size_t)m * DD + n] = acc[mt][nt][reg] + biasv;
            }
        }
    }
}

// ---------------------------------------------------------------------------
// MFMA flash attention v9 = r11's v7 structure (best measured) on COMPACTED
// K/V. Per q-tile the key loop runs only over the nkeys = pfx[qt*64+63]
// unmasked keys (block-uniform bound); causal mask uses the ORIGINAL key
// index cidx[c] <= q (pad test gone — all compact keys are unmasked; tail
// slots have cidx = SS so p = 0, and Kc/VTc tails are zero-filled so no
// NaN can enter PV). Everything else byte-identical to r11's flash_mfma7.
// ---------------------------------------------------------------------------
__global__ __launch_bounds__(256) void flash_mfma9(
    const bf16* __restrict__ Qh,   // [B,H,S,HD]
    const bf16* __restrict__ Kc,   // [B,H,Sc,HD] compacted keys (zero tail)
    const bf16* __restrict__ VTc,  // [B,H,HD,Sc] compacted V^T (zero tail)
    const int*  __restrict__ cidx, // [B,S] compact->original key index
    const int*  __restrict__ pfx,  // [B,S] inclusive unmasked-count
    bf16* __restrict__ attn)       // [B,S,D]
{
    __shared__ short Ks[2][64 * 64];    // 16 KB (double-buffered)
    __shared__ short Vs[2][64 * 64];    // 16 KB
    __shared__ short Pld[4][16 * 64];   // 8 KB per-wave P tiles

    const int tid  = threadIdx.x;
    const int lane = tid & 63;
    const int wave = tid >> 6;
    const int xcd = blockIdx.x & 7;
    const int idx = blockIdx.x >> 3;        // 0..127
    const int bh  = (xcd << 2) | (idx & 3); // 4 heads per XCD group
    const int qt  = 31 - (idx >> 2);        // 64-row q-tile, longest first
    const int q0  = qt * 64 + wave * 16;
    const int b_  = bh >> 4;
    const int h_  = bh & 15;

    const int g  = lane >> 4;   // 0..3
    const int fr = lane & 15;
    const int k8 = g * 8;

    short* myP = Pld[wave];

    // Q fragments (2 dim-halves), pre-scaled by 1/sqrt(64)=0.125
    const bf16* qbase = Qh + ((size_t)bh * SS + q0 + fr) * HD + k8;
    short8 qf[2];
#pragma unroll
    for (int hh = 0; hh < 2; ++hh) {
        short8 rawq = *(const short8*)((const short*)qbase + hh * 32);
#pragma unroll
        for (int j = 0; j < 8; ++j) qf[hh][j] = f2bs(bs2f(rawq[j]) * 0.125f);
    }

    const int* corow = cidx + b_ * SS;
    const int nkeys  = pfx[b_ * SS + qt * 64 + 63];   // block-uniform, >= 1
    const short* kbh = (const short*)(Kc  + (size_t)bh * SS * HD);
    const short* vbh = (const short*)(VTc + (size_t)bh * HD * SS);

    const int l8  = lane >> 3;          // 0..7
    const int sch = (lane & 7) ^ l8;    // pre-swizzled source chunk
    auto stageKV = [&](int buf, int kb) {
#pragma unroll
        for (int j = 0; j < 2; ++j) {
            const int r = wave * 16 + j * 8;          // wave-uniform base row
            GL16(kbh + (size_t)(kb + r + l8) * HD + sch * 8, &Ks[buf][r * 64]);
            GL16(vbh + (size_t)(r + l8) * SS + kb + sch * 8, &Vs[buf][r * 64]);
        }
    };

    floatx4 o[4] = {{0,0,0,0},{0,0,0,0},{0,0,0,0},{0,0,0,0}};
    float l_acc[4] = {0.f, 0.f, 0.f, 0.f};

    stageKV(0, 0);
    asm volatile("s_waitcnt vmcnt(0)" ::: "memory");
    __syncthreads();

    for (int kb = 0; kb < nkeys; kb += 64) {
        const int cur = (kb >> 6) & 1;
        if (kb + 64 < nkeys) stageKV(cur ^ 1, kb + 64);

        const short* Kt = Ks[cur];
        const short* Vc = Vs[cur];

        floatx4 c[4];
        __builtin_amdgcn_s_setprio(1);
#pragma unroll
        for (int t = 0; t < 4; ++t) {
            short8 kf0 = *(const short8*)&Kt[(t * 16 + fr) * 64 + ((g       ^ (fr & 7)) << 3)];
            short8 kf1 = *(const short8*)&Kt[(t * 16 + fr) * 64 + (((g + 4) ^ (fr & 7)) << 3)];
            floatx4 cc = {0, 0, 0, 0};
            cc = __builtin_amdgcn_mfma_f32_16x16x32_bf16(qf[0], kf0, cc, 0, 0, 0);
            cc = __builtin_amdgcn_mfma_f32_16x16x32_bf16(qf[1], kf1, cc, 0, 0, 0);
            c[t] = cc;
        }
        __builtin_amdgcn_s_setprio(0);

        int ko[4];
#pragma unroll
        for (int t = 0; t < 4; ++t) ko[t] = corow[kb + t * 16 + fr];  // orig idx

#pragma unroll
        for (int reg = 0; reg < 4; ++reg) {
            const int q   = q0 + g * 4 + reg;
            const int row = g * 4 + reg;
#pragma unroll
            for (int t = 0; t < 4; ++t) {
                const float p = (ko[t] <= q) ? __expf(c[t][reg]) : 0.f;
                l_acc[reg] += p;
                const int col = t * 16 + fr;
                myP[row * 64 + (((col >> 3) ^ (row & 7)) << 3) + (col & 7)] = f2bs(p);
            }
        }

        short8 pf0 = *(const short8*)&myP[fr * 64 + ((g       ^ (fr & 7)) << 3)];
        short8 pf1 = *(const short8*)&myP[fr * 64 + (((g + 4) ^ (fr & 7)) << 3)];
        __builtin_amdgcn_s_setprio(1);
#pragma unroll
        for (int n = 0; n < 4; ++n) {
            short8 vf0 = *(const short8*)&Vc[(n * 16 + fr) * 64 + ((g       ^ (fr & 7)) << 3)];
            short8 vf1 = *(const short8*)&Vc[(n * 16 + fr) * 64 + (((g + 4) ^ (fr & 7)) << 3)];
            o[n] = __builtin_amdgcn_mfma_f32_16x16x32_bf16(pf0, vf0, o[n], 0, 0, 0);
            o[n] = __builtin_amdgcn_mfma_f32_16x16x32_bf16(pf1, vf1, o[n], 0, 0, 0);
        }
        __builtin_amdgcn_s_setprio(0);

        asm volatile("s_waitcnt vmcnt(0)" ::: "memory");
        __syncthreads();
    }

    float inv[4];
#pragma unroll
    for (int reg = 0; reg < 4; ++reg) {
        float l = l_acc[reg];
#pragma unroll
        for (int off = 1; off < 16; off <<= 1) l += __shfl_xor(l, off);
        inv[reg] = 1.f / fmaxf(l, 1e-38f);
    }
#pragma unroll
    for (int n = 0; n < 4; ++n) {
#pragma unroll
        for (int reg = 0; reg < 4; ++reg) {
            const int q = q0 + g * 4 + reg;
            attn[((size_t)(b_ * SS + q)) * DD + h_ * HD + n * 16 + fr] =
                __float2bfloat16(o[n][reg] * inv[reg]);
        }
    }
}

// ---------------------------------------------------------------------------
extern "C" void kernel_launch(void* const* d_in, const int* in_sizes, int n_in,
                              void* d_out, int out_size, void* d_ws, size_t ws_size,
                              hipStream_t stream) {
    const float* x   = (const float*)d_in[0];
    const int*   pad = (const int*)  d_in[1];
    const float* Wq  = (const float*)d_in[2];
    const float* bq  = (const float*)d_in[3];
    const float* Wk  = (const float*)d_in[4];
    const float* bk  = (const float*)d_in[5];
    const float* Wv  = (const float*)d_in[6];
    const float* bv  = (const float*)d_in[7];
    const float* Wo  = (const float*)d_in[8];
    const float* bo  = (const float*)d_in[9];
    float* out = (float*)d_out;                  // fp32 output

    const size_t NELEM = (size_t)BB * HH * SS * HD;  // 4,194,304
    bf16* Qh   = (bf16*)d_ws;
    bf16* Kc   = Qh + NELEM;        // compacted K (zero-filled tail)
    bf16* VTc  = Kc + NELEM;        // compacted V^T (zero-filled tail)
    bf16* attn = VTc + NELEM;
    int*  cidx = (int*)(attn + NELEM);      // [B][S]
    int*  pfx  = cidx + BB * SS;            // [B][S]
    // Scratch in d_out (16.78 MB): Wcat 6.29 MB + Xb 8.39 MB, both consumed
    // before o_gemm2 overwrites d_out with the final fp32 result.
    short* Wcat = (short*)d_out;
    short* Xb   = (short*)d_out + (size_t)NQKV * DD;

    // Wob after the idx arrays if ws permits (single merged convert);
    // else alias Qh and convert after flash (fallback).
    const size_t ws_need = 4 * NELEM * sizeof(bf16) + 2 * (size_t)BB * SS * sizeof(int)
                         + (size_t)DD * DD * sizeof(short);
    const bool big_ws = ws_size >= ws_need;
    short* Wob = big_ws ? (short*)(pfx + BB * SS) : (short*)Qh;

    convert_all<<<2048, 256, 0, stream>>>(Wq, Wk, Wv, x, Wo, Wcat, Xb,
                                          big_ws ? Wob : nullptr);

    build_idx<<<BB, 256, 0, stream>>>(pad, cidx, pfx);

    // zero Kc+VTc (contiguous) so compact tails are 0 (no NaN via 0*garbage)
    hipMemsetAsync(Kc, 0, 2 * NELEM * sizeof(bf16), stream);

    dim3 gq(MM / 128, NQKV / 64);
    qkv_gemm2<<<gq, 256, 0, stream>>>(Xb, Wcat, bq, bk, bv, pad, pfx,
                                      Qh, Kc, VTc);

    flash_mfma9<<<BB * HH * 32, 256, 0, stream>>>(Qh, Kc, VTc, cidx, pfx, attn);

    if (!big_ws) convert_w<<<512, 256, 0, stream>>>(Wo, Wob);

    dim3 go(MM / 128, DD / 64);
    o_gemm2<<<go, 256, 0, stream>>>((const short*)attn, Wob, bo, out);
}

// Round 14
// 184.075 us; speedup vs baseline: 1.1140x; 1.0290x over previous
//
#include <hip/hip_runtime.h>
#include <hip/hip_bf16.h>

// Problem constants (reference: B=2, S=2048, D=1024, H=16, HD=64)
#define BB 2
#define SS 2048
#define DD 1024
#define HH 16
#define HD 64
#define MM (BB * SS)   // 4096 rows in all GEMMs
#define NQKV 3072      // fused QKV output columns

typedef __attribute__((ext_vector_type(8))) short short8;   // 8 x bf16 frag
typedef __attribute__((ext_vector_type(4))) short s16x4;
typedef __attribute__((ext_vector_type(4))) float floatx4;  // MFMA C/D frag
typedef __attribute__((ext_vector_type(4))) float f32x4;
using bf16 = __hip_bfloat16;

__device__ __forceinline__ float b2f(bf16 x) { return __bfloat162float(x); }
__device__ __forceinline__ short f2bs(float x) {
    bf16 h = __float2bfloat16(x);
    return *reinterpret_cast<short*>(&h);
}
__device__ __forceinline__ float bs2f(short s) {
    bf16 h; *reinterpret_cast<short*>(&h) = s; return __bfloat162float(h);
}

// LDS tiles addressed in 16B chunks (8 shorts), XOR swizzle (chunk ^ (row&7)).
__device__ __forceinline__ int lds_off(int row, int chunk) {
    return row * 64 + ((chunk ^ (row & 7)) * 8);
}

// Direct global->LDS async copy, 16B per lane.
#define GL16(gp, lp)                                                        \
    __builtin_amdgcn_global_load_lds(                                       \
        (const __attribute__((address_space(1))) void*)(gp),                \
        (__attribute__((address_space(3))) void*)(lp), 16, 0, 0)

// ---------------------------------------------------------------------------
// Merged converter r20: Wcat | Xb | Wob conversion PLUS the per-batch
// compaction scan (former build_idx) in ONE launch. Blocks 0..BB-1 run the
// scan; blocks BB.. run the grid-stride convert. 6 -> 4 total dispatches.
// ---------------------------------------------------------------------------
#define N_WCAT (NQKV * DD / 4)
#define N_X    (MM * DD / 4)
#define N_WOB  (DD * DD / 4)

__global__ __launch_bounds__(256) void convert_all(
    const float* __restrict__ Wq, const float* __restrict__ Wk,
    const float* __restrict__ Wv, const float* __restrict__ X,
    const float* __restrict__ Wo, const int* __restrict__ pad,
    int* __restrict__ cidx, int* __restrict__ pfx,
    short* __restrict__ wcat, short* __restrict__ xb, short* wob)
{
    if (blockIdx.x < BB) {
        // ---- compaction scan for batch b (former build_idx) ----
        const int b   = blockIdx.x;
        const int tid = threadIdx.x;
        __shared__ int part[256];
        const int* pr = pad + b * SS;
        int* ci = cidx + b * SS;
        int* pf = pfx + b * SS;

        const int s0 = tid * 8;
        int loc[8]; int sum = 0;
#pragma unroll
        for (int j = 0; j < 8; ++j) { loc[j] = (pr[s0 + j] == 0) ? 1 : 0; sum += loc[j]; }
        part[tid] = sum;
        __syncthreads();
        for (int off = 1; off < 256; off <<= 1) {
            const int v   = part[tid];
            const int add = (tid >= off) ? part[tid - off] : 0;
            __syncthreads();
            part[tid] = v + add;
            __syncthreads();
        }
        int run = (tid > 0) ? part[tid - 1] : 0;
#pragma unroll
        for (int j = 0; j < 8; ++j) {
            run += loc[j];
            pf[s0 + j] = run;
            if (loc[j]) ci[run - 1] = s0 + j;
        }
        const int total = part[255];
        for (int j = total + tid; j < SS; j += 256) ci[j] = SS;  // sentinel
        return;
    }

    // ---- grid-stride conversion over the remaining blocks ----
    const int total = N_WCAT + N_X + (wob ? N_WOB : 0);
    const int stride = (gridDim.x - BB) * blockDim.x;
    for (int i = (blockIdx.x - BB) * blockDim.x + threadIdx.x; i < total; i += stride) {
        f32x4 v; short* dp;
        if (i < N_WCAT) {
            const int e = i * 4;
            const int z = e >> 20;
            const int off = e & 0xFFFFF;
            const float* src = (z == 0) ? Wq : (z == 1) ? Wk : Wv;
            v = *(const f32x4*)(src + off);
            dp = wcat + e;
        } else if (i < N_WCAT + N_X) {
            const int e = (i - N_WCAT) * 4;
            v = *(const f32x4*)(X + e);
            dp = xb + e;
        } else {
            const int e = (i - N_WCAT - N_X) * 4;
            v = *(const f32x4*)(Wo + e);
            dp = wob + e;
        }
        s16x4 o; o[0] = f2bs(v[0]); o[1] = f2bs(v[1]); o[2] = f2bs(v[2]); o[3] = f2bs(v[3]);
        *(s16x4*)dp = o;
    }
}

// Fallback single converter (only when ws too small to hoist Wob).
__global__ __launch_bounds__(256) void convert_w(
    const float* __restrict__ W, short* __restrict__ dst)
{
    const int stride = gridDim.x * blockDim.x;
    for (int i = blockIdx.x * blockDim.x + threadIdx.x; i < DD * DD / 4; i += stride) {
        f32x4 v = *(const f32x4*)(W + i * 4);
        s16x4 o; o[0] = f2bs(v[0]); o[1] = f2bs(v[1]); o[2] = f2bs(v[2]); o[3] = f2bs(v[3]);
        *(s16x4*)(dst + i * 4) = o;
    }
}

// ---------------------------------------------------------------------------
// Fused QKV GEMM (r19 structure). r20 epilogue: BIJECTIVE compact write —
// unmasked row s -> slot pfx[s]-1 (K/V value), masked row s -> tail slot
// btot + s - pfx[s] (ZERO). Every compact slot written exactly once, so the
// 16.8 MB Kc/VTc memset dispatch is eliminated while flash's zero-tail
// invariant (no NaN via 0*garbage) is preserved.
// ---------------------------------------------------------------------------
__global__ __launch_bounds__(256, 6) void qkv_gemm2(
    const short* __restrict__ Xb, const short* __restrict__ Wcat,
    const float* __restrict__ bq, const float* __restrict__ bk, const float* __restrict__ bv,
    const int* __restrict__ pad, const int* __restrict__ pfx,
    bf16* __restrict__ outQ, bf16* __restrict__ outKc, bf16* __restrict__ outVTc)
{
    __shared__ short As[128 * 64];   // 16 KB
    __shared__ short Bs[64 * 64];    // 8 KB

    const int tid  = threadIdx.x;
    const int lane = tid & 63;
    const int wave = tid >> 6;
    const int wm   = wave & 1;
    const int wn   = wave >> 1;
    const int g    = lane >> 4;
    const int fr   = lane & 15;

    const int m0 = blockIdx.x * 128;
    const int n0 = blockIdx.y * 64;

    const int l8  = lane >> 3;
    const int sch = (lane & 7) ^ l8;
    const short* agl = Xb   + (size_t)(m0 + l8) * DD + sch * 8;
    const short* bgl = Wcat + (size_t)(n0 + l8) * DD + sch * 8;

    floatx4 acc[4][2];
#pragma unroll
    for (int i = 0; i < 4; ++i)
#pragma unroll
        for (int j = 0; j < 2; ++j) acc[i][j] = (floatx4){0.f, 0.f, 0.f, 0.f};

    for (int kb = 0; kb < DD; kb += 64) {
        __syncthreads();
#pragma unroll
        for (int j = 0; j < 4; ++j) {
            const int r = wave * 32 + j * 8;
            GL16(agl + (size_t)r * DD + kb, &As[r * 64]);
        }
#pragma unroll
        for (int j = 0; j < 2; ++j) {
            const int r = wave * 16 + j * 8;
            GL16(bgl + (size_t)r * DD + kb, &Bs[r * 64]);
        }
        __syncthreads();

#pragma unroll
        for (int kk = 0; kk < 2; ++kk) {
            const int kc = kk * 4 + g;
            short8 af[4], bf[2];
#pragma unroll
            for (int t = 0; t < 4; ++t)
                af[t] = *(const short8*)&As[lds_off(wm * 64 + t * 16 + fr, kc)];
#pragma unroll
            for (int u = 0; u < 2; ++u)
                bf[u] = *(const short8*)&Bs[lds_off(wn * 32 + u * 16 + fr, kc)];
#pragma unroll
            for (int mt = 0; mt < 4; ++mt)
#pragma unroll
                for (int nt = 0; nt < 2; ++nt)
                    acc[mt][nt] = __builtin_amdgcn_mfma_f32_16x16x32_bf16(
                        af[mt], bf[nt], acc[mt][nt], 0, 0, 0);
        }
    }

    const int bblk = m0 >> 11;                    // block-uniform batch index
    const int btot = pfx[bblk * SS + SS - 1];     // unmasked count for batch

#pragma unroll
    for (int nt = 0; nt < 2; ++nt) {
        const int n  = n0 + wn * 32 + nt * 16 + fr;
        const int z  = n >> 10;          // uniform per block (n0 64-aligned)
        const int nn = n & 1023;
        const int h_ = nn >> 6;
        const int d_ = nn & 63;
        const float biasv = ((z == 0) ? bq : (z == 1) ? bk : bv)[nn];
#pragma unroll
        for (int mt = 0; mt < 4; ++mt) {
#pragma unroll
            for (int reg = 0; reg < 4; ++reg) {
                const int m  = m0 + wm * 64 + mt * 16 + g * 4 + reg;
                const int s_ = m & (SS - 1);
                const float v = acc[mt][nt][reg] + biasv;
                if (z == 0) {
                    outQ[((size_t)((bblk * HH + h_) * SS + s_)) * HD + d_] =
                        __float2bfloat16(v);
                } else {
                    const int ps  = pfx[bblk * SS + s_];
                    const bool um = (pad[bblk * SS + s_] == 0);
                    const int cs  = um ? (ps - 1) : (btot + s_ - ps);  // bijective
                    const short w = um ? f2bs(v) : (short)0;
                    if (z == 1)
                        ((short*)outKc)[((size_t)((bblk * HH + h_) * SS + cs)) * HD + d_] = w;
                    else
                        ((short*)outVTc)[((size_t)((bblk * HH + h_) * HD + d_)) * SS + cs] = w;
                }
            }
        }
    }
}

// ---------------------------------------------------------------------------
// Output projection (r19, unchanged).
// ---------------------------------------------------------------------------
__global__ __launch_bounds__(256, 6) void o_gemm2(
    const short* __restrict__ A, const short* __restrict__ Wob,
    const float* __restrict__ bias, float* __restrict__ out)
{
    __shared__ short As[128 * 64];
    __shared__ short Bs[64 * 64];

    const int tid  = threadIdx.x;
    const int lane = tid & 63;
    const int wave = tid >> 6;
    const int wm   = wave & 1;
    const int wn   = wave >> 1;
    const int g    = lane >> 4;
    const int fr   = lane & 15;

    const int m0 = blockIdx.x * 128;
    const int n0 = blockIdx.y * 64;

    const int l8  = lane >> 3;
    const int sch = (lane & 7) ^ l8;
    const short* agl = A   + (size_t)(m0 + l8) * DD + sch * 8;
    const short* bgl = Wob + (size_t)(n0 + l8) * DD + sch * 8;

    floatx4 acc[4][2];
#pragma unroll
    for (int i = 0; i < 4; ++i)
#pragma unroll
        for (int j = 0; j < 2; ++j) acc[i][j] = (floatx4){0.f, 0.f, 0.f, 0.f};

    for (int kb = 0; kb < DD; kb += 64) {
        __syncthreads();
#pragma unroll
        for (int j = 0; j < 4; ++j) {
            const int r = wave * 32 + j * 8;
            GL16(agl + (size_t)r * DD + kb, &As[r * 64]);
        }
#pragma unroll
        for (int j = 0; j < 2; ++j) {
            const int r = wave * 16 + j * 8;
            GL16(bgl + (size_t)r * DD + kb, &Bs[r * 64]);
        }
        __syncthreads();

#pragma unroll
        for (int kk = 0; kk < 2; ++kk) {
            const int kc = kk * 4 + g;
            short8 af[4], bf[2];
#pragma unroll
            for (int t = 0; t < 4; ++t)
                af[t] = *(const short8*)&As[lds_off(wm * 64 + t * 16 + fr, kc)];
#pragma unroll
            for (int u = 0; u < 2; ++u)
                bf[u] = *(const short8*)&Bs[lds_off(wn * 32 + u * 16 + fr, kc)];
#pragma unroll
            for (int mt = 0; mt < 4; ++mt)
#pragma unroll
                for (int nt = 0; nt < 2; ++nt)
                    acc[mt][nt] = __builtin_amdgcn_mfma_f32_16x16x32_bf16(
                        af[mt], bf[nt], acc[mt][nt], 0, 0, 0);
        }
    }

#pragma unroll
    for (int nt = 0; nt < 2; ++nt) {
        const int n = n0 + wn * 32 + nt * 16 + fr;
        const float biasv = bias[n];
#pragma unroll
        for (int mt = 0; mt < 4; ++mt) {
#pragma unroll
            for (int reg = 0; reg < 4; ++reg) {
                const int m = m0 + wm * 64 + mt * 16 + g * 4 + reg;
                out[(size_t)m * DD + n] = acc[mt][nt][reg] + biasv;
            }
        }
    }
}

// ---------------------------------------------------------------------------
// MFMA flash attention v9 (r13, unchanged): compacted K/V, per-tile key loop
// over nkeys = pfx[qt*64+63]; causal mask on original index cidx[c] <= q.
// ---------------------------------------------------------------------------
__global__ __launch_bounds__(256) void flash_mfma9(
    const bf16* __restrict__ Qh,   // [B,H,S,HD]
    const bf16* __restrict__ Kc,   // [B,H,Sc,HD] compacted keys (zero tail)
    const bf16* __restrict__ VTc,  // [B,H,HD,Sc] compacted V^T (zero tail)
    const int*  __restrict__ cidx, // [B,S] compact->original key index
    const int*  __restrict__ pfx,  // [B,S] inclusive unmasked-count
    bf16* __restrict__ attn)       // [B,S,D]
{
    __shared__ short Ks[2][64 * 64];    // 16 KB (double-buffered)
    __shared__ short Vs[2][64 * 64];    // 16 KB
    __shared__ short Pld[4][16 * 64];   // 8 KB per-wave P tiles

    const int tid  = threadIdx.x;
    const int lane = tid & 63;
    const int wave = tid >> 6;
    const int xcd = blockIdx.x & 7;
    const int idx = blockIdx.x >> 3;        // 0..127
    const int bh  = (xcd << 2) | (idx & 3); // 4 heads per XCD group
    const int qt  = 31 - (idx >> 2);        // 64-row q-tile, longest first
    const int q0  = qt * 64 + wave * 16;
    const int b_  = bh >> 4;
    const int h_  = bh & 15;

    const int g  = lane >> 4;   // 0..3
    const int fr = lane & 15;
    const int k8 = g * 8;

    short* myP = Pld[wave];

    // Q fragments (2 dim-halves), pre-scaled by 1/sqrt(64)=0.125
    const bf16* qbase = Qh + ((size_t)bh * SS + q0 + fr) * HD + k8;
    short8 qf[2];
#pragma unroll
    for (int hh = 0; hh < 2; ++hh) {
        short8 rawq = *(const short8*)((const short*)qbase + hh * 32);
#pragma unroll
        for (int j = 0; j < 8; ++j) qf[hh][j] = f2bs(bs2f(rawq[j]) * 0.125f);
    }

    const int* corow = cidx + b_ * SS;
    const int nkeys  = pfx[b_ * SS + qt * 64 + 63];   // block-uniform, >= 1
    const short* kbh = (const short*)(Kc  + (size_t)bh * SS * HD);
    const short* vbh = (const short*)(VTc + (size_t)bh * HD * SS);

    const int l8  = lane >> 3;          // 0..7
    const int sch = (lane & 7) ^ l8;    // pre-swizzled source chunk
    auto stageKV = [&](int buf, int kb) {
#pragma unroll
        for (int j = 0; j < 2; ++j) {
            const int r = wave * 16 + j * 8;          // wave-uniform base row
            GL16(kbh + (size_t)(kb + r + l8) * HD + sch * 8, &Ks[buf][r * 64]);
            GL16(vbh + (size_t)(r + l8) * SS + kb + sch * 8, &Vs[buf][r * 64]);
        }
    };

    floatx4 o[4] = {{0,0,0,0},{0,0,0,0},{0,0,0,0},{0,0,0,0}};
    float l_acc[4] = {0.f, 0.f, 0.f, 0.f};

    stageKV(0, 0);
    asm volatile("s_waitcnt vmcnt(0)" ::: "memory");
    __syncthreads();

    for (int kb = 0; kb < nkeys; kb += 64) {
        const int cur = (kb >> 6) & 1;
        if (kb + 64 < nkeys) stageKV(cur ^ 1, kb + 64);

        const short* Kt = Ks[cur];
        const short* Vc = Vs[cur];

        floatx4 c[4];
        __builtin_amdgcn_s_setprio(1);
#pragma unroll
        for (int t = 0; t < 4; ++t) {
            short8 kf0 = *(const short8*)&Kt[(t * 16 + fr) * 64 + ((g       ^ (fr & 7)) << 3)];
            short8 kf1 = *(const short8*)&Kt[(t * 16 + fr) * 64 + (((g + 4) ^ (fr & 7)) << 3)];
            floatx4 cc = {0, 0, 0, 0};
            cc = __builtin_amdgcn_mfma_f32_16x16x32_bf16(qf[0], kf0, cc, 0, 0, 0);
            cc = __builtin_amdgcn_mfma_f32_16x16x32_bf16(qf[1], kf1, cc, 0, 0, 0);
            c[t] = cc;
        }
        __builtin_amdgcn_s_setprio(0);

        int ko[4];
#pragma unroll
        for (int t = 0; t < 4; ++t) ko[t] = corow[kb + t * 16 + fr];  // orig idx

#pragma unroll
        for (int reg = 0; reg < 4; ++reg) {
            const int q   = q0 + g * 4 + reg;
            const int row = g * 4 + reg;
#pragma unroll
            for (int t = 0; t < 4; ++t) {
                const float p = (ko[t] <= q) ? __expf(c[t][reg]) : 0.f;
                l_acc[reg] += p;
                const int col = t * 16 + fr;
                myP[row * 64 + (((col >> 3) ^ (row & 7)) << 3) + (col & 7)] = f2bs(p);
            }
        }

        short8 pf0 = *(const short8*)&myP[fr * 64 + ((g       ^ (fr & 7)) << 3)];
        short8 pf1 = *(const short8*)&myP[fr * 64 + (((g + 4) ^ (fr & 7)) << 3)];
        __builtin_amdgcn_s_setprio(1);
#pragma unroll
        for (int n = 0; n < 4; ++n) {
            short8 vf0 = *(const short8*)&Vc[(n * 16 + fr) * 64 + ((g       ^ (fr & 7)) << 3)];
            short8 vf1 = *(const short8*)&Vc[(n * 16 + fr) * 64 + (((g + 4) ^ (fr & 7)) << 3)];
            o[n] = __builtin_amdgcn_mfma_f32_16x16x32_bf16(pf0, vf0, o[n], 0, 0, 0);
            o[n] = __builtin_amdgcn_mfma_f32_16x16x32_bf16(pf1, vf1, o[n], 0, 0, 0);
        }
        __builtin_amdgcn_s_setprio(0);

        asm volatile("s_waitcnt vmcnt(0)" ::: "memory");
        __syncthreads();
    }

    float inv[4];
#pragma unroll
    for (int reg = 0; reg < 4; ++reg) {
        float l = l_acc[reg];
#pragma unroll
        for (int off = 1; off < 16; off <<= 1) l += __shfl_xor(l, off);
        inv[reg] = 1.f / fmaxf(l, 1e-38f);
    }
#pragma unroll
    for (int n = 0; n < 4; ++n) {
#pragma unroll
        for (int reg = 0; reg < 4; ++reg) {
            const int q = q0 + g * 4 + reg;
            attn[((size_t)(b_ * SS + q)) * DD + h_ * HD + n * 16 + fr] =
                __float2bfloat16(o[n][reg] * inv[reg]);
        }
    }
}

// ---------------------------------------------------------------------------
extern "C" void kernel_launch(void* const* d_in, const int* in_sizes, int n_in,
                              void* d_out, int out_size, void* d_ws, size_t ws_size,
                              hipStream_t stream) {
    const float* x   = (const float*)d_in[0];
    const int*   pad = (const int*)  d_in[1];
    const float* Wq  = (const float*)d_in[2];
    const float* bq  = (const float*)d_in[3];
    const float* Wk  = (const float*)d_in[4];
    const float* bk  = (const float*)d_in[5];
    const float* Wv  = (const float*)d_in[6];
    const float* bv  = (const float*)d_in[7];
    const float* Wo  = (const float*)d_in[8];
    const float* bo  = (const float*)d_in[9];
    float* out = (float*)d_out;                  // fp32 output

    const size_t NELEM = (size_t)BB * HH * SS * HD;  // 4,194,304
    bf16* Qh   = (bf16*)d_ws;
    bf16* Kc   = Qh + NELEM;        // compacted K (bijective zero-tail)
    bf16* VTc  = Kc + NELEM;        // compacted V^T (bijective zero-tail)
    bf16* attn = VTc + NELEM;
    int*  cidx = (int*)(attn + NELEM);      // [B][S]
    int*  pfx  = cidx + BB * SS;            // [B][S]
    // Scratch in d_out (16.78 MB): Wcat 6.29 MB + Xb 8.39 MB, both consumed
    // before o_gemm2 overwrites d_out with the final fp32 result.
    short* Wcat = (short*)d_out;
    short* Xb   = (short*)d_out + (size_t)NQKV * DD;

    // Wob after the idx arrays if ws permits (single merged convert);
    // else alias Qh and convert after flash (fallback).
    const size_t ws_need = 4 * NELEM * sizeof(bf16) + 2 * (size_t)BB * SS * sizeof(int)
                         + (size_t)DD * DD * sizeof(short);
    const bool big_ws = ws_size >= ws_need;
    short* Wob = big_ws ? (short*)(pfx + BB * SS) : (short*)Qh;

    convert_all<<<2048 + BB, 256, 0, stream>>>(Wq, Wk, Wv, x, Wo, pad,
                                               cidx, pfx, Wcat, Xb,
                                               big_ws ? Wob : nullptr);

    dim3 gq(MM / 128, NQKV / 64);
    qkv_gemm2<<<gq, 256, 0, stream>>>(Xb, Wcat, bq, bk, bv, pad, pfx,
                                      Qh, Kc, VTc);

    flash_mfma9<<<BB * HH * 32, 256, 0, stream>>>(Qh, Kc, VTc, cidx, pfx, attn);

    if (!big_ws) convert_w<<<512, 256, 0, stream>>>(Wo, Wob);

    dim3 go(MM / 128, DD / 64);
    o_gemm2<<<go, 256, 0, stream>>>((const short*)attn, Wob, bo, out);
}